// Round 4
// baseline (182.577 us; speedup 1.0000x reference)
//
#include <hip/hip_runtime.h>

#define B_   1024
#define L_   2048
#define IND_ 64
#define H_   4
#define K_   64

// ---------------- prep 1: w_eff[b][h][i] = (1/4) * sum_d q[b,h,d] * Wh[i, h*16+d]
__global__ __launch_bounds__(64) void prep_weff_k(const float* __restrict__ target,
                                                  const float* __restrict__ Wq,
                                                  const float* __restrict__ Wh,
                                                  float* __restrict__ weff) {
  const int b = blockIdx.x;
  const int t = threadIdx.x;  // 0..63
  __shared__ float tgt[64];
  __shared__ double q[64];
  tgt[t] = target[b * 64 + t];
  __syncthreads();
  double acc = 0.0;
#pragma unroll
  for (int j = 0; j < 64; ++j) acc += (double)tgt[j] * (double)Wq[j * 64 + t];
  q[t] = acc;
  __syncthreads();
#pragma unroll
  for (int h = 0; h < H_; ++h) {
    double a2 = 0.0;
#pragma unroll
    for (int d = 0; d < 16; ++d) a2 += q[h * 16 + d] * (double)Wh[t * 64 + h * 16 + d];
    weff[((size_t)b * H_ + h) * 64 + t] = (float)(a2 * 0.25);  // fold 1/SCALE
  }
}

// ---------------- prep 2: M[h][i][j] = sum_d Wv[i, h*16+d] * Wo[h*16+d, j]
__global__ __launch_bounds__(256) void prep_M_k(const float* __restrict__ Wv,
                                                const float* __restrict__ Wo,
                                                float* __restrict__ M) {
  const int idx = blockIdx.x * 256 + threadIdx.x;  // 0..16383
  const int h = idx >> 12, i = (idx >> 6) & 63, j = idx & 63;
  double a = 0.0;
#pragma unroll
  for (int d = 0; d < 16; ++d)
    a += (double)Wv[i * 64 + h * 16 + d] * (double)Wo[(h * 16 + d) * 64 + j];
  M[idx] = (float)a;
}

// monotone float->uint key (order-preserving), and inverse
__device__ __forceinline__ unsigned f2key(float s) {
  unsigned u = __float_as_uint(s);
  return (u & 0x80000000u) ? ~u : (u | 0x80000000u);
}
__device__ __forceinline__ float key2f(unsigned k) {
  unsigned u = (k & 0x80000000u) ? (k & 0x7FFFFFFFu) : ~k;
  return __uint_as_float(u);
}

__device__ __forceinline__ void gload_lds16(const float* g, float* l) {
  __builtin_amdgcn_global_load_lds(
      (const __attribute__((address_space(1))) void*)g,
      (__attribute__((address_space(3))) void*)l, 16, 0, 0);
}

// wave-uniform value -> SGPR
__device__ __forceinline__ float to_sgpr(float x) {
  return __uint_as_float(__builtin_amdgcn_readfirstlane(__float_as_uint(x)));
}

// ---------------- main kernel: one block per b; wave w handles head w
__global__ __launch_bounds__(256, 4) void attn_main_k(const float* __restrict__ seq,
                                                      const int* __restrict__ mask,
                                                      const float* __restrict__ weff,
                                                      const float* __restrict__ M,
                                                      float* __restrict__ out) {
  __shared__ float stage[2][64 * 64];  // 32 KB, double-buffered tile
  __shared__ int   sidx[H_][K_];
  __shared__ float sw[H_][K_];
  __shared__ float svec[H_][64];
  __shared__ float part[H_][64];

  const int b = blockIdx.x;
  const int tid = threadIdx.x;
  const int w = tid >> 6;   // wave id == head id
  const int ln = tid & 63;
  const float* __restrict__ seqb = seq + (size_t)b * (L_ * IND_);
  const int* __restrict__ maskb = mask + (size_t)b * L_;

  // stage tile `t` into buffer `bi`: linear LDS dest (DMA), inverse-swizzled
  // global source. LDS slot (r, c) holds global column c^(r&7) of row r.
  // Each wave issues exactly 4 global_load_lds -> vmcnt bookkeeping below.
#define STAGE(bi, t)                                                          \
  {                                                                           \
    _Pragma("unroll") for (int k = 0; k < 4; ++k) {                           \
      const int f = (k << 8) + tid;                                           \
      const int r = f >> 4;                                                   \
      const int c = f & 15;                                                   \
      gload_lds16(seqb + (((t) << 6) + r) * 64 + ((c ^ (r & 7)) << 2),        \
                  &stage[bi][f << 2]);                                        \
    }                                                                         \
  }

  // ---- pre-loop loads, fully CONSUMED before any DMA is issued, so the
  // ---- compiler inserts no vmem waits inside the pipelined loop.
  unsigned mbits = 0;
#pragma unroll
  for (int t = 0; t < 32; ++t) mbits |= (maskb[(t << 6) + ln] ? 1u : 0u) << t;

  float wef[64];  // wave-uniform -> SGPRs via readfirstlane
  {
    const float4* wp4 = (const float4*)(weff + ((size_t)b * H_ + w) * 64);
#pragma unroll
    for (int i = 0; i < 16; ++i) {
      const float4 v = wp4[i];
      wef[4 * i + 0] = to_sgpr(v.x);
      wef[4 * i + 1] = to_sgpr(v.y);
      wef[4 * i + 2] = to_sgpr(v.z);
      wef[4 * i + 3] = to_sgpr(v.w);
    }
  }

  // ---- prologue: 2 tiles in flight
  STAGE(0, 0);
  STAGE(1, 1);
  __builtin_amdgcn_sched_barrier(0);

  // ---------- scoring: counted-vmcnt pipeline, loads stay in flight ----------
  unsigned kk[32];
  const unsigned KNEG = f2key(-1e9f);
  const int rs = ln & 7;
#pragma unroll
  for (int t = 0; t < 32; ++t) {
    // wait: this wave's 4 loads of tile t arrived (tile t+1's 4 may remain)
    if (t < 31) asm volatile("s_waitcnt vmcnt(4)");
    else        asm volatile("s_waitcnt vmcnt(0)");
    __builtin_amdgcn_sched_barrier(0);
    __builtin_amdgcn_s_barrier();  // all waves' quarters of tile t present
    __builtin_amdgcn_sched_barrier(0);

    const float* rp = &stage[t & 1][ln << 6];  // lane = row
    float acc = 0.f;
#pragma unroll
    for (int c = 0; c < 16; ++c) {
      const float4 v = *reinterpret_cast<const float4*>(rp + ((c ^ rs) << 2));
      acc = fmaf(v.x, wef[4 * c + 0], acc);
      acc = fmaf(v.y, wef[4 * c + 1], acc);
      acc = fmaf(v.z, wef[4 * c + 2], acc);
      acc = fmaf(v.w, wef[4 * c + 3], acc);
    }
    kk[t] = ((mbits >> t) & 1u) ? f2key(acc) : KNEG;

    __builtin_amdgcn_sched_barrier(0);
    __builtin_amdgcn_s_barrier();  // all waves done reading buf[t&1]
    __builtin_amdgcn_sched_barrier(0);
    if (t + 2 < 32) STAGE(t & 1, t + 2);  // overwrite now-free buffer
  }

  // ---------- selection (per wave): exact 64th-largest via bitwise binary search ----------
  unsigned kmax = 0u;
#pragma unroll
  for (int j = 0; j < 32; ++j) kmax = max(kmax, kk[j]);
#pragma unroll
  for (int off = 32; off >= 1; off >>= 1)
    kmax = max(kmax, (unsigned)__shfl_xor((int)kmax, off, 64));
  const float smax = key2f(kmax);

  unsigned lo = 0u, hi = 0xFFFFFFFFu;
  while (lo < hi) {  // find max t with count(key >= t) >= 64
    const unsigned span = hi - lo;
    const unsigned mid = lo + (span >> 1) + (span & 1u);
    int c = 0;
#pragma unroll
    for (int j = 0; j < 32; ++j) c += (kk[j] >= mid) ? 1 : 0;
#pragma unroll
    for (int off = 32; off >= 1; off >>= 1) c += __shfl_xor(c, off, 64);
    if (c >= K_) lo = mid; else hi = mid - 1;
  }
  const unsigned V = lo;
  int cg = 0;
#pragma unroll
  for (int j = 0; j < 32; ++j) cg += (kk[j] > V) ? 1 : 0;
#pragma unroll
  for (int off = 32; off >= 1; off >>= 1) cg += __shfl_xor(cg, off, 64);
  const int m = K_ - cg;  // #ties (==V) to take, lowest index first (lax.top_k stable)

  {
    const unsigned long long lmlt = (1ull << ln) - 1ull;
    int gbase = 0, etaken = 0;
#pragma unroll
    for (int j = 0; j < 32; ++j) {
      const unsigned key = kk[j];
      const int l = ln + (j << 6);  // lane order == index order within chunk
      const bool gt = key > V;
      const bool eq = key == V;
      const unsigned long long bgt = __ballot(gt);
      const unsigned long long beq = __ballot(eq);
      if (gt) {
        const int pos = gbase + __popcll(bgt & lmlt);
        sidx[w][pos] = l;
        sw[w][pos] = expf(key2f(key) - smax);
      }
      const int navail = __popcll(beq);
      const int take = min(m - etaken, navail);
      if (eq) {
        const int rk = __popcll(beq & lmlt);
        if (rk < take) {
          const int pos = 63 - (etaken + rk);  // ties fill from the back
          sidx[w][pos] = l;
          sw[w][pos] = expf(key2f(key) - smax);
        }
      }
      gbase += __popcll(bgt);
      etaken += take;
    }
  }
  // no barrier: sidx/sw written and read by the same wave

  // ---------- gather + softmax-weighted sum of raw seq rows ----------
  {
    const int cg4 = ln & 15;  // float4 column group
    const int rg = ln >> 4;   // row subgroup 0..3
    float4 sv = make_float4(0.f, 0.f, 0.f, 0.f);
    float z = 0.f;
#pragma unroll
    for (int j = 0; j < 16; ++j) {
      const int sl = (j << 2) + rg;
      const int idx = sidx[w][sl];
      const float wt = sw[w][sl];
      const float4 v =
          *reinterpret_cast<const float4*>(seqb + (size_t)idx * 64 + (cg4 << 2));
      sv.x = fmaf(wt, v.x, sv.x);
      sv.y = fmaf(wt, v.y, sv.y);
      sv.z = fmaf(wt, v.z, sv.z);
      sv.w = fmaf(wt, v.w, sv.w);
      z += wt;
    }
#pragma unroll
    for (int off = 16; off <= 32; off <<= 1) {
      sv.x += __shfl_xor(sv.x, off, 64);
      sv.y += __shfl_xor(sv.y, off, 64);
      sv.z += __shfl_xor(sv.z, off, 64);
      sv.w += __shfl_xor(sv.w, off, 64);
      z += __shfl_xor(z, off, 64);
    }
    if (rg == 0) {  // lanes 0..15 hold the reduced result
      const float inv = 1.f / z;
      svec[w][(cg4 << 2) + 0] = sv.x * inv;
      svec[w][(cg4 << 2) + 1] = sv.y * inv;
      svec[w][(cg4 << 2) + 2] = sv.z * inv;
      svec[w][(cg4 << 2) + 3] = sv.w * inv;
    }
  }
  __syncthreads();

  // ---------- epilogue: out[b,:] = sum_h svec_h @ M_h ----------
  {
    float o = 0.f;
    const float* __restrict__ Mh = M + (w << 12);
#pragma unroll
    for (int i = 0; i < 64; ++i) o = fmaf(svec[w][i], Mh[(i << 6) + ln], o);
    part[w][ln] = o;
  }
  __syncthreads();
  if (tid < 64)
    out[(size_t)b * 64 + tid] = part[0][tid] + part[1][tid] + part[2][tid] + part[3][tid];
#undef STAGE
}

extern "C" void kernel_launch(void* const* d_in, const int* in_sizes, int n_in,
                              void* d_out, int out_size, void* d_ws, size_t ws_size,
                              hipStream_t stream) {
  const float* target = (const float*)d_in[0];
  const float* seq    = (const float*)d_in[1];
  const int*   mask   = (const int*)d_in[2];
  const float* Wq     = (const float*)d_in[3];
  const float* Wh     = (const float*)d_in[4];
  const float* Wv     = (const float*)d_in[5];
  const float* Wo     = (const float*)d_in[6];
  float* out  = (float*)d_out;
  float* weff = (float*)d_ws;                   // B*H*64 floats = 1 MB
  float* M    = weff + (size_t)B_ * H_ * 64;    // H*64*64 floats = 64 KB

  prep_weff_k<<<B_, 64, 0, stream>>>(target, Wq, Wh, weff);
  prep_M_k<<<64, 256, 0, stream>>>(Wv, Wo, M);
  attn_main_k<<<B_, 256, 0, stream>>>(seq, mask, weff, M, out);
}

// Round 6
// 152.958 us; speedup vs baseline: 1.1936x; 1.1936x over previous
//
#include <hip/hip_runtime.h>

#define B_   1024
#define L_   2048
#define IND_ 64
#define H_   4
#define K_   64

// ---------------- prep 1: w_eff[b][h][i] = (1/4) * sum_d q[b,h,d] * Wh[i, h*16+d]
__global__ __launch_bounds__(64) void prep_weff_k(const float* __restrict__ target,
                                                  const float* __restrict__ Wq,
                                                  const float* __restrict__ Wh,
                                                  float* __restrict__ weff) {
  const int b = blockIdx.x;
  const int t = threadIdx.x;  // 0..63
  __shared__ float tgt[64];
  __shared__ double q[64];
  tgt[t] = target[b * 64 + t];
  __syncthreads();
  double acc = 0.0;
#pragma unroll
  for (int j = 0; j < 64; ++j) acc += (double)tgt[j] * (double)Wq[j * 64 + t];
  q[t] = acc;
  __syncthreads();
#pragma unroll
  for (int h = 0; h < H_; ++h) {
    double a2 = 0.0;
#pragma unroll
    for (int d = 0; d < 16; ++d) a2 += q[h * 16 + d] * (double)Wh[t * 64 + h * 16 + d];
    weff[((size_t)b * H_ + h) * 64 + t] = (float)(a2 * 0.25);  // fold 1/SCALE
  }
}

// ---------------- prep 2: M[h][i][j] = sum_d Wv[i, h*16+d] * Wo[h*16+d, j]
__global__ __launch_bounds__(256) void prep_M_k(const float* __restrict__ Wv,
                                                const float* __restrict__ Wo,
                                                float* __restrict__ M) {
  const int idx = blockIdx.x * 256 + threadIdx.x;  // 0..16383
  const int h = idx >> 12, i = (idx >> 6) & 63, j = idx & 63;
  double a = 0.0;
#pragma unroll
  for (int d = 0; d < 16; ++d)
    a += (double)Wv[i * 64 + h * 16 + d] * (double)Wo[(h * 16 + d) * 64 + j];
  M[idx] = (float)a;
}

// monotone float->uint key (order-preserving), and inverse
__device__ __forceinline__ unsigned f2key(float s) {
  unsigned u = __float_as_uint(s);
  return (u & 0x80000000u) ? ~u : (u | 0x80000000u);
}
__device__ __forceinline__ float key2f(unsigned k) {
  unsigned u = (k & 0x80000000u) ? (k & 0x7FFFFFFFu) : ~k;
  return __uint_as_float(u);
}

// DPP move within 16-lane rows; invalid source lanes read 0 (bound_ctrl=true).
// row_shl:N (ctrl 0x100+N): dst[i] = src[i+N]  -> data moves toward LOWER
// lanes, so a +=-chain accumulates the full 16-lane sum into lane 0.
// (round-5 bug: row_shr moves toward HIGHER lanes; lane 0 got only its own
//  partial -> wrong scores. Canonical AMD reduce lands the sum in lane 15.)
template <int CTRL>
__device__ __forceinline__ float dpp_mov(float x) {
  return __int_as_float(
      __builtin_amdgcn_update_dpp(0, __float_as_int(x), CTRL, 0xf, 0xf, true));
}

// ---------------- main kernel: one block per b; 4 waves
// Phase 1 (barrier-free): wave w streams rows [512w, 512w+512), scoring ALL 4
// heads via coalesced 1KB loads + DPP 16-lane reduce. One barrier total.
__global__ __launch_bounds__(256, 4) void attn_main_k(const float* __restrict__ seq,
                                                      const int* __restrict__ mask,
                                                      const float* __restrict__ weff,
                                                      const float* __restrict__ M,
                                                      float* __restrict__ out) {
  __shared__ float scores[H_ * L_];  // 32 KB scoreboard
  __shared__ int   sidx[H_][K_];
  __shared__ float sw[H_][K_];
  __shared__ float svec[H_][64];
  __shared__ float part[H_][64];

  const int b = blockIdx.x;
  const int tid = threadIdx.x;
  const int w = tid >> 6;   // wave id (phase1: row slice; later: head id)
  const int ln = tid & 63;
  const int g = ln >> 4;    // row subgroup 0..3
  const int j = ln & 15;    // float4 column index
  const float* __restrict__ seqb = seq + (size_t)b * (L_ * IND_);
  const int* __restrict__ maskb = mask + (size_t)b * L_;

  // per-lane wef fragment: wefv[h][e] = weff[b][h][4j+e]  (16 VGPRs)
  float wefv[H_][4];
  {
    const float* wp = weff + (size_t)b * (H_ * 64) + (j << 2);
#pragma unroll
    for (int h = 0; h < H_; ++h) {
      const float4 v = *reinterpret_cast<const float4*>(wp + (h << 6));
      wefv[h][0] = v.x; wefv[h][1] = v.y; wefv[h][2] = v.z; wefv[h][3] = v.w;
    }
  }

  // ---------- phase 1: scoring, zero barriers ----------
  const int rbase = (w << 9) + g;                       // this lane's first row
  const float* __restrict__ lp = seqb + rbase * 64 + (j << 2);
#pragma unroll 4
  for (int s = 0; s < 128; ++s) {
    // 4 consecutive rows per step; 64 lanes cover 1 KB contiguous
    const float4 v = *reinterpret_cast<const float4*>(lp + (s << 8));
#pragma unroll
    for (int h = 0; h < H_; ++h) {
      float p = v.x * wefv[h][0];
      p = fmaf(v.y, wefv[h][1], p);
      p = fmaf(v.z, wefv[h][2], p);
      p = fmaf(v.w, wefv[h][3], p);
      // directed 16-lane reduce toward j==0 (VALU pipe only)
      p += dpp_mov<0x108>(p);  // row_shl:8
      p += dpp_mov<0x104>(p);  // row_shl:4
      p += dpp_mov<0x102>(p);  // row_shl:2
      p += dpp_mov<0x101>(p);  // row_shl:1
      if (j == 0) scores[(h << 11) + rbase + (s << 2)] = p;
    }
  }

  // mask bits for this lane's selection rows
  unsigned mbits = 0;
#pragma unroll
  for (int t = 0; t < 32; ++t) mbits |= (maskb[(t << 6) + ln] ? 1u : 0u) << t;

  __syncthreads();  // scoreboard complete; wave w now owns head w

  // ---------- selection: exact 64th-largest via bitwise binary search ----------
  unsigned kk[32];
  const unsigned KNEG = f2key(-1e9f);
#pragma unroll
  for (int t = 0; t < 32; ++t) {
    const float s_ = scores[(w << 11) + (t << 6) + ln];
    kk[t] = ((mbits >> t) & 1u) ? f2key(s_) : KNEG;
  }

  unsigned kmax = 0u;
#pragma unroll
  for (int q = 0; q < 32; ++q) kmax = max(kmax, kk[q]);
#pragma unroll
  for (int off = 32; off >= 1; off >>= 1)
    kmax = max(kmax, (unsigned)__shfl_xor((int)kmax, off, 64));
  const float smax = key2f(kmax);

  unsigned lo = 0u, hi = 0xFFFFFFFFu;
  while (lo < hi) {  // find max t with count(key >= t) >= 64
    const unsigned span = hi - lo;
    const unsigned mid = lo + (span >> 1) + (span & 1u);
    int c = 0;
#pragma unroll
    for (int q = 0; q < 32; ++q) c += (kk[q] >= mid) ? 1 : 0;
#pragma unroll
    for (int off = 32; off >= 1; off >>= 1) c += __shfl_xor(c, off, 64);
    if (c >= K_) lo = mid; else hi = mid - 1;
  }
  const unsigned V = lo;
  int cg = 0;
#pragma unroll
  for (int q = 0; q < 32; ++q) cg += (kk[q] > V) ? 1 : 0;
#pragma unroll
  for (int off = 32; off >= 1; off >>= 1) cg += __shfl_xor(cg, off, 64);
  const int m = K_ - cg;  // #ties (==V) to take, lowest index first (lax.top_k stable)

  {
    const unsigned long long lmlt = (1ull << ln) - 1ull;
    int gbase = 0, etaken = 0;
#pragma unroll
    for (int q = 0; q < 32; ++q) {
      const unsigned key = kk[q];
      const int l = ln + (q << 6);  // lane order == index order within chunk
      const bool gt = key > V;
      const bool eq = key == V;
      const unsigned long long bgt = __ballot(gt);
      const unsigned long long beq = __ballot(eq);
      if (gt) {
        const int pos = gbase + __popcll(bgt & lmlt);
        sidx[w][pos] = l;
        sw[w][pos] = expf(key2f(key) - smax);
      }
      const int navail = __popcll(beq);
      const int take = min(m - etaken, navail);
      if (eq) {
        const int rk = __popcll(beq & lmlt);
        if (rk < take) {
          const int pos = 63 - (etaken + rk);  // ties fill from the back
          sidx[w][pos] = l;
          sw[w][pos] = expf(key2f(key) - smax);
        }
      }
      gbase += __popcll(bgt);
      etaken += take;
    }
  }
  // no barrier: sidx/sw written and read by the same wave

  // ---------- gather + softmax-weighted sum of raw seq rows ----------
  {
    const int cg4 = ln & 15;  // float4 column group
    const int rg = ln >> 4;   // row subgroup 0..3
    float4 sv = make_float4(0.f, 0.f, 0.f, 0.f);
    float z = 0.f;
#pragma unroll
    for (int q = 0; q < 16; ++q) {
      const int sl = (q << 2) + rg;
      const int idx = sidx[w][sl];
      const float wt = sw[w][sl];
      const float4 v =
          *reinterpret_cast<const float4*>(seqb + (size_t)idx * 64 + (cg4 << 2));
      sv.x = fmaf(wt, v.x, sv.x);
      sv.y = fmaf(wt, v.y, sv.y);
      sv.z = fmaf(wt, v.z, sv.z);
      sv.w = fmaf(wt, v.w, sv.w);
      z += wt;
    }
#pragma unroll
    for (int off = 16; off <= 32; off <<= 1) {
      sv.x += __shfl_xor(sv.x, off, 64);
      sv.y += __shfl_xor(sv.y, off, 64);
      sv.z += __shfl_xor(sv.z, off, 64);
      sv.w += __shfl_xor(sv.w, off, 64);
      z += __shfl_xor(z, off, 64);
    }
    if (rg == 0) {  // lanes 0..15 hold the reduced result
      const float inv = 1.f / z;
      svec[w][(cg4 << 2) + 0] = sv.x * inv;
      svec[w][(cg4 << 2) + 1] = sv.y * inv;
      svec[w][(cg4 << 2) + 2] = sv.z * inv;
      svec[w][(cg4 << 2) + 3] = sv.w * inv;
    }
  }
  __syncthreads();

  // ---------- epilogue: out[b,:] = sum_h svec_h @ M_h ----------
  {
    float o = 0.f;
    const float* __restrict__ Mh = M + (w << 12);
#pragma unroll
    for (int i = 0; i < 64; ++i) o = fmaf(svec[w][i], Mh[(i << 6) + ln], o);
    part[w][ln] = o;
  }
  __syncthreads();
  if (tid < 64)
    out[(size_t)b * 64 + tid] = part[0][tid] + part[1][tid] + part[2][tid] + part[3][tid];
}

extern "C" void kernel_launch(void* const* d_in, const int* in_sizes, int n_in,
                              void* d_out, int out_size, void* d_ws, size_t ws_size,
                              hipStream_t stream) {
  const float* target = (const float*)d_in[0];
  const float* seq    = (const float*)d_in[1];
  const int*   mask   = (const int*)d_in[2];
  const float* Wq     = (const float*)d_in[3];
  const float* Wh     = (const float*)d_in[4];
  const float* Wv     = (const float*)d_in[5];
  const float* Wo     = (const float*)d_in[6];
  float* out  = (float*)d_out;
  float* weff = (float*)d_ws;                   // B*H*64 floats = 1 MB
  float* M    = weff + (size_t)B_ * H_ * 64;    // H*64*64 floats = 64 KB

  prep_weff_k<<<B_, 64, 0, stream>>>(target, Wq, Wh, weff);
  prep_M_k<<<64, 256, 0, stream>>>(Wv, Wo, M);
  attn_main_k<<<B_, 256, 0, stream>>>(seq, mask, weff, M, out);
}

// Round 7
// 141.345 us; speedup vs baseline: 1.2917x; 1.0822x over previous
//
#include <hip/hip_runtime.h>

#define B_   1024
#define L_   2048
#define IND_ 64
#define H_   4
#define K_   64

// ---------------- prep 1: w_eff[b][h][i] = (1/4) * sum_d q[b,h,d] * Wh[i, h*16+d]
__global__ __launch_bounds__(64) void prep_weff_k(const float* __restrict__ target,
                                                  const float* __restrict__ Wq,
                                                  const float* __restrict__ Wh,
                                                  float* __restrict__ weff) {
  const int b = blockIdx.x;
  const int t = threadIdx.x;  // 0..63
  __shared__ float tgt[64];
  __shared__ double q[64];
  tgt[t] = target[b * 64 + t];
  __syncthreads();
  double acc = 0.0;
#pragma unroll
  for (int j = 0; j < 64; ++j) acc += (double)tgt[j] * (double)Wq[j * 64 + t];
  q[t] = acc;
  __syncthreads();
#pragma unroll
  for (int h = 0; h < H_; ++h) {
    double a2 = 0.0;
#pragma unroll
    for (int d = 0; d < 16; ++d) a2 += q[h * 16 + d] * (double)Wh[t * 64 + h * 16 + d];
    weff[((size_t)b * H_ + h) * 64 + t] = (float)(a2 * 0.25);  // fold 1/SCALE
  }
}

// ---------------- prep 2: M[h][i][j] = sum_d Wv[i, h*16+d] * Wo[h*16+d, j]
__global__ __launch_bounds__(256) void prep_M_k(const float* __restrict__ Wv,
                                                const float* __restrict__ Wo,
                                                float* __restrict__ M) {
  const int idx = blockIdx.x * 256 + threadIdx.x;  // 0..16383
  const int h = idx >> 12, i = (idx >> 6) & 63, j = idx & 63;
  double a = 0.0;
#pragma unroll
  for (int d = 0; d < 16; ++d)
    a += (double)Wv[i * 64 + h * 16 + d] * (double)Wo[(h * 16 + d) * 64 + j];
  M[idx] = (float)a;
}

// monotone float->uint key (order-preserving), and inverse
__device__ __forceinline__ unsigned f2key(float s) {
  unsigned u = __float_as_uint(s);
  return (u & 0x80000000u) ? ~u : (u | 0x80000000u);
}
__device__ __forceinline__ float key2f(unsigned k) {
  unsigned u = (k & 0x80000000u) ? (k & 0x7FFFFFFFu) : ~k;
  return __uint_as_float(u);
}

// DPP move within 16-lane rows; invalid source lanes read 0 (bound_ctrl=true).
// row_shl:N (ctrl 0x100+N): dst[i] = src[i+N] -> accumulates the 16-lane sum
// into lane 0 of each group (verified round 6).
template <int CTRL>
__device__ __forceinline__ float dpp_mov(float x) {
  return __int_as_float(
      __builtin_amdgcn_update_dpp(0, __float_as_int(x), CTRL, 0xf, 0xf, true));
}

// ---------------- main kernel: one block per b; 4 waves
// Phase 1 (barrier-free): wave w streams rows [512w, 512w+512) scoring ALL 4
// heads. Explicit 8-deep load batches keep >=4 KB/wave of HBM traffic in
// flight (R6 was latency-bound at ~2-4 loads in flight). One barrier total.
__global__ __launch_bounds__(256, 4) void attn_main_k(const float* __restrict__ seq,
                                                      const int* __restrict__ mask,
                                                      const float* __restrict__ weff,
                                                      const float* __restrict__ M,
                                                      float* __restrict__ out) {
  __shared__ float scores[H_ * L_];  // 32 KB scoreboard
  __shared__ int   sidx[H_][K_];
  __shared__ float sw[H_][K_];
  __shared__ float svec[H_][64];
  __shared__ float part[H_][64];

  const int b = blockIdx.x;
  const int tid = threadIdx.x;
  const int w = tid >> 6;   // wave id (phase1: row slice; later: head id)
  const int ln = tid & 63;
  const int g = ln >> 4;    // row subgroup 0..3
  const int j = ln & 15;    // float4 column index
  const float* __restrict__ seqb = seq + (size_t)b * (L_ * IND_);
  const int* __restrict__ maskb = mask + (size_t)b * L_;

  // per-lane wef fragment: wefv[h][e] = weff[b][h][4j+e]  (16 VGPRs)
  float wefv[H_][4];
  {
    const float* wp = weff + (size_t)b * (H_ * 64) + (j << 2);
#pragma unroll
    for (int h = 0; h < H_; ++h) {
      const float4 v = *reinterpret_cast<const float4*>(wp + (h << 6));
      wefv[h][0] = v.x; wefv[h][1] = v.y; wefv[h][2] = v.z; wefv[h][3] = v.w;
    }
  }

  // ---------- phase 1: scoring, zero barriers, 8-deep load batches ----------
  const int rbase = (w << 9) + g;  // this lane's first row
  // float4 pointer: element (rbase*64 + 4j)/4 = rbase*16 + j; step stride 64
  const float4* __restrict__ lp4 =
      reinterpret_cast<const float4*>(seqb) + (rbase << 4) + j;
#pragma unroll 1
  for (int sb = 0; sb < 16; ++sb) {
    float4 vv[8];
#pragma unroll
    for (int u = 0; u < 8; ++u) vv[u] = lp4[((sb << 3) + u) << 6];  // 8 loads in flight
#pragma unroll
    for (int u = 0; u < 8; ++u) {
      const int s = (sb << 3) + u;
      const float4 v = vv[u];
#pragma unroll
      for (int h = 0; h < H_; ++h) {
        float p = v.x * wefv[h][0];
        p = fmaf(v.y, wefv[h][1], p);
        p = fmaf(v.z, wefv[h][2], p);
        p = fmaf(v.w, wefv[h][3], p);
        // directed 16-lane reduce toward j==0 (VALU pipe only)
        p += dpp_mov<0x108>(p);  // row_shl:8
        p += dpp_mov<0x104>(p);  // row_shl:4
        p += dpp_mov<0x102>(p);  // row_shl:2
        p += dpp_mov<0x101>(p);  // row_shl:1
        if (j == 0) scores[(h << 11) + rbase + (s << 2)] = p;
      }
    }
  }

  // mask bits for this lane's selection rows
  unsigned mbits = 0;
#pragma unroll
  for (int t = 0; t < 32; ++t) mbits |= (maskb[(t << 6) + ln] ? 1u : 0u) << t;

  __syncthreads();  // scoreboard complete; wave w now owns head w

  // ---------- selection: exact 64th-largest via bitwise binary search ----------
  unsigned kk[32];
  const unsigned KNEG = f2key(-1e9f);
#pragma unroll
  for (int t = 0; t < 32; ++t) {
    const float s_ = scores[(w << 11) + (t << 6) + ln];
    kk[t] = ((mbits >> t) & 1u) ? f2key(s_) : KNEG;
  }

  unsigned kmax = 0u;
#pragma unroll
  for (int q = 0; q < 32; ++q) kmax = max(kmax, kk[q]);
#pragma unroll
  for (int off = 32; off >= 1; off >>= 1)
    kmax = max(kmax, (unsigned)__shfl_xor((int)kmax, off, 64));
  const float smax = key2f(kmax);

  unsigned lo = 0u, hi = 0xFFFFFFFFu;
  while (lo < hi) {  // find max t with count(key >= t) >= 64
    const unsigned span = hi - lo;
    const unsigned mid = lo + (span >> 1) + (span & 1u);
    int c = 0;
#pragma unroll
    for (int q = 0; q < 32; ++q) c += (kk[q] >= mid) ? 1 : 0;
#pragma unroll
    for (int off = 32; off >= 1; off >>= 1) c += __shfl_xor(c, off, 64);
    if (c >= K_) lo = mid; else hi = mid - 1;
  }
  const unsigned V = lo;
  int cg = 0;
#pragma unroll
  for (int q = 0; q < 32; ++q) cg += (kk[q] > V) ? 1 : 0;
#pragma unroll
  for (int off = 32; off >= 1; off >>= 1) cg += __shfl_xor(cg, off, 64);
  const int m = K_ - cg;  // #ties (==V) to take, lowest index first (lax.top_k stable)

  {
    const unsigned long long lmlt = (1ull << ln) - 1ull;
    int gbase = 0, etaken = 0;
#pragma unroll
    for (int q = 0; q < 32; ++q) {
      const unsigned key = kk[q];
      const int l = ln + (q << 6);  // lane order == index order within chunk
      const bool gt = key > V;
      const bool eq = key == V;
      const unsigned long long bgt = __ballot(gt);
      const unsigned long long beq = __ballot(eq);
      if (gt) {
        const int pos = gbase + __popcll(bgt & lmlt);
        sidx[w][pos] = l;
        sw[w][pos] = expf(key2f(key) - smax);
      }
      const int navail = __popcll(beq);
      const int take = min(m - etaken, navail);
      if (eq) {
        const int rk = __popcll(beq & lmlt);
        if (rk < take) {
          const int pos = 63 - (etaken + rk);  // ties fill from the back
          sidx[w][pos] = l;
          sw[w][pos] = expf(key2f(key) - smax);
        }
      }
      gbase += __popcll(bgt);
      etaken += take;
    }
  }
  // no barrier: sidx/sw written and read by the same wave

  // ---------- gather + softmax-weighted sum of raw seq rows ----------
  {
    const int cg4 = ln & 15;  // float4 column group
    const int rg = ln >> 4;   // row subgroup 0..3
    float4 sv = make_float4(0.f, 0.f, 0.f, 0.f);
    float z = 0.f;
#pragma unroll
    for (int q = 0; q < 16; ++q) {
      const int sl = (q << 2) + rg;
      const int idx = sidx[w][sl];
      const float wt = sw[w][sl];
      const float4 v =
          *reinterpret_cast<const float4*>(seqb + (size_t)idx * 64 + (cg4 << 2));
      sv.x = fmaf(wt, v.x, sv.x);
      sv.y = fmaf(wt, v.y, sv.y);
      sv.z = fmaf(wt, v.z, sv.z);
      sv.w = fmaf(wt, v.w, sv.w);
      z += wt;
    }
#pragma unroll
    for (int off = 16; off <= 32; off <<= 1) {
      sv.x += __shfl_xor(sv.x, off, 64);
      sv.y += __shfl_xor(sv.y, off, 64);
      sv.z += __shfl_xor(sv.z, off, 64);
      sv.w += __shfl_xor(sv.w, off, 64);
      z += __shfl_xor(z, off, 64);
    }
    if (rg == 0) {  // lanes 0..15 hold the reduced result
      const float inv = 1.f / z;
      svec[w][(cg4 << 2) + 0] = sv.x * inv;
      svec[w][(cg4 << 2) + 1] = sv.y * inv;
      svec[w][(cg4 << 2) + 2] = sv.z * inv;
      svec[w][(cg4 << 2) + 3] = sv.w * inv;
    }
  }
  __syncthreads();

  // ---------- epilogue: out[b,:] = sum_h svec_h @ M_h ----------
  {
    float o = 0.f;
    const float* __restrict__ Mh = M + (w << 12);
#pragma unroll
    for (int i = 0; i < 64; ++i) o = fmaf(svec[w][i], Mh[(i << 6) + ln], o);
    part[w][ln] = o;
  }
  __syncthreads();
  if (tid < 64)
    out[(size_t)b * 64 + tid] = part[0][tid] + part[1][tid] + part[2][tid] + part[3][tid];
}

extern "C" void kernel_launch(void* const* d_in, const int* in_sizes, int n_in,
                              void* d_out, int out_size, void* d_ws, size_t ws_size,
                              hipStream_t stream) {
  const float* target = (const float*)d_in[0];
  const float* seq    = (const float*)d_in[1];
  const int*   mask   = (const int*)d_in[2];
  const float* Wq     = (const float*)d_in[3];
  const float* Wh     = (const float*)d_in[4];
  const float* Wv     = (const float*)d_in[5];
  const float* Wo     = (const float*)d_in[6];
  float* out  = (float*)d_out;
  float* weff = (float*)d_ws;                   // B*H*64 floats = 1 MB
  float* M    = weff + (size_t)B_ * H_ * 64;    // H*64*64 floats = 64 KB

  prep_weff_k<<<B_, 64, 0, stream>>>(target, Wq, Wh, weff);
  prep_M_k<<<64, 256, 0, stream>>>(Wv, Wo, M);
  attn_main_k<<<B_, 256, 0, stream>>>(seq, mask, weff, M, out);
}

// Round 8
// 137.524 us; speedup vs baseline: 1.3276x; 1.0278x over previous
//
#include <hip/hip_runtime.h>

#define B_   1024
#define L_   2048
#define IND_ 64
#define H_   4
#define K_   64

// ---------------- prep 1: w_eff[b][h][i] = (1/4) * sum_d q[b,h,d] * Wh[i, h*16+d]
__global__ __launch_bounds__(64) void prep_weff_k(const float* __restrict__ target,
                                                  const float* __restrict__ Wq,
                                                  const float* __restrict__ Wh,
                                                  float* __restrict__ weff) {
  const int b = blockIdx.x;
  const int t = threadIdx.x;  // 0..63
  __shared__ float tgt[64];
  __shared__ double q[64];
  tgt[t] = target[b * 64 + t];
  __syncthreads();
  double acc = 0.0;
#pragma unroll
  for (int j = 0; j < 64; ++j) acc += (double)tgt[j] * (double)Wq[j * 64 + t];
  q[t] = acc;
  __syncthreads();
#pragma unroll
  for (int h = 0; h < H_; ++h) {
    double a2 = 0.0;
#pragma unroll
    for (int d = 0; d < 16; ++d) a2 += q[h * 16 + d] * (double)Wh[t * 64 + h * 16 + d];
    weff[((size_t)b * H_ + h) * 64 + t] = (float)(a2 * 0.25);  // fold 1/SCALE
  }
}

// ---------------- prep 2: M[h][i][j] = sum_d Wv[i, h*16+d] * Wo[h*16+d, j]
__global__ __launch_bounds__(256) void prep_M_k(const float* __restrict__ Wv,
                                                const float* __restrict__ Wo,
                                                float* __restrict__ M) {
  const int idx = blockIdx.x * 256 + threadIdx.x;  // 0..16383
  const int h = idx >> 12, i = (idx >> 6) & 63, j = idx & 63;
  double a = 0.0;
#pragma unroll
  for (int d = 0; d < 16; ++d)
    a += (double)Wv[i * 64 + h * 16 + d] * (double)Wo[(h * 16 + d) * 64 + j];
  M[idx] = (float)a;
}

// monotone float->uint key (order-preserving), and inverse
__device__ __forceinline__ unsigned f2key(float s) {
  unsigned u = __float_as_uint(s);
  return (u & 0x80000000u) ? ~u : (u | 0x80000000u);
}
__device__ __forceinline__ float key2f(unsigned k) {
  unsigned u = (k & 0x80000000u) ? (k & 0x7FFFFFFFu) : ~k;
  return __uint_as_float(u);
}

// DPP move within 16-lane rows; invalid source lanes read 0 (bound_ctrl=true).
// row_shl:N (ctrl 0x100+N): dst[i] = src[i+N] -> accumulates the 16-lane sum
// into lane 0 of each group (verified round 6).
template <int CTRL>
__device__ __forceinline__ float dpp_mov(float x) {
  return __int_as_float(
      __builtin_amdgcn_update_dpp(0, __float_as_int(x), CTRL, 0xf, 0xf, true));
}

// ---------------- main kernel: one block per b; 4 waves
// Phase 1 (barrier-free): wave w streams rows [512w, 512w+512) scoring ALL 4
// heads. Double-buffered 8-deep load batches (vvA/vvB, static indices only)
// keep ~8 KB/wave of HBM traffic in flight CONTINUOUSLY (R7 dropped to zero
// outstanding during each batch's compute). One barrier total.
__global__ __launch_bounds__(256, 4) void attn_main_k(const float* __restrict__ seq,
                                                      const int* __restrict__ mask,
                                                      const float* __restrict__ weff,
                                                      const float* __restrict__ M,
                                                      float* __restrict__ out) {
  __shared__ float scores[H_ * L_];  // 32 KB scoreboard
  __shared__ int   sidx[H_][K_];
  __shared__ float sw[H_][K_];
  __shared__ float svec[H_][64];
  __shared__ float part[H_][64];

  const int b = blockIdx.x;
  const int tid = threadIdx.x;
  const int w = tid >> 6;   // wave id (phase1: row slice; later: head id)
  const int ln = tid & 63;
  const int g = ln >> 4;    // row subgroup 0..3
  const int j = ln & 15;    // float4 column index
  const float* __restrict__ seqb = seq + (size_t)b * (L_ * IND_);
  const int* __restrict__ maskb = mask + (size_t)b * L_;

  // per-lane wef fragment: wefv[h][e] = weff[b][h][4j+e]  (16 VGPRs)
  float wefv[H_][4];
  {
    const float* wp = weff + (size_t)b * (H_ * 64) + (j << 2);
#pragma unroll
    for (int h = 0; h < H_; ++h) {
      const float4 v = *reinterpret_cast<const float4*>(wp + (h << 6));
      wefv[h][0] = v.x; wefv[h][1] = v.y; wefv[h][2] = v.z; wefv[h][3] = v.w;
    }
  }

  // ---------- phase 1: scoring, zero barriers, pipelined 8-deep batches ----
  const int rbase = (w << 9) + g;  // this lane's first row
  const float4* __restrict__ lp4 =
      reinterpret_cast<const float4*>(seqb) + (rbase << 4) + j;

  float4 vvA[8], vvB[8];

#define LOADB(V, SB)                                                          \
  {                                                                           \
    _Pragma("unroll") for (int u = 0; u < 8; ++u)                             \
        V[u] = lp4[(((SB) << 3) + u) << 6];                                   \
  }
#define COMPUTE(V, SB)                                                        \
  {                                                                           \
    _Pragma("unroll") for (int u = 0; u < 8; ++u) {                           \
      const int s = ((SB) << 3) + u;                                          \
      const float4 v = V[u];                                                  \
      _Pragma("unroll") for (int h = 0; h < H_; ++h) {                        \
        float p = v.x * wefv[h][0];                                           \
        p = fmaf(v.y, wefv[h][1], p);                                         \
        p = fmaf(v.z, wefv[h][2], p);                                         \
        p = fmaf(v.w, wefv[h][3], p);                                         \
        p += dpp_mov<0x108>(p); /* row_shl:8 */                               \
        p += dpp_mov<0x104>(p); /* row_shl:4 */                               \
        p += dpp_mov<0x102>(p); /* row_shl:2 */                               \
        p += dpp_mov<0x101>(p); /* row_shl:1 */                               \
        if (j == 0) scores[(h << 11) + rbase + (s << 2)] = p;                 \
      }                                                                       \
    }                                                                         \
  }

  LOADB(vvA, 0);
  LOADB(vvB, 1);  COMPUTE(vvA, 0);
  LOADB(vvA, 2);  COMPUTE(vvB, 1);
  LOADB(vvB, 3);  COMPUTE(vvA, 2);
  LOADB(vvA, 4);  COMPUTE(vvB, 3);
  LOADB(vvB, 5);  COMPUTE(vvA, 4);
  LOADB(vvA, 6);  COMPUTE(vvB, 5);
  LOADB(vvB, 7);  COMPUTE(vvA, 6);
  LOADB(vvA, 8);  COMPUTE(vvB, 7);
  LOADB(vvB, 9);  COMPUTE(vvA, 8);
  LOADB(vvA, 10); COMPUTE(vvB, 9);
  LOADB(vvB, 11); COMPUTE(vvA, 10);
  LOADB(vvA, 12); COMPUTE(vvB, 11);
  LOADB(vvB, 13); COMPUTE(vvA, 12);
  LOADB(vvA, 14); COMPUTE(vvB, 13);
  LOADB(vvB, 15); COMPUTE(vvA, 14);
                  COMPUTE(vvB, 15);
#undef LOADB
#undef COMPUTE

  // mask bits for this lane's selection rows
  unsigned mbits = 0;
#pragma unroll
  for (int t = 0; t < 32; ++t) mbits |= (maskb[(t << 6) + ln] ? 1u : 0u) << t;

  __syncthreads();  // scoreboard complete; wave w now owns head w

  // ---------- selection: exact 64th-largest via bitwise binary search ----------
  unsigned kk[32];
  const unsigned KNEG = f2key(-1e9f);
#pragma unroll
  for (int t = 0; t < 32; ++t) {
    const float s_ = scores[(w << 11) + (t << 6) + ln];
    kk[t] = ((mbits >> t) & 1u) ? f2key(s_) : KNEG;
  }

  unsigned kmax = 0u;
#pragma unroll
  for (int q = 0; q < 32; ++q) kmax = max(kmax, kk[q]);
#pragma unroll
  for (int off = 32; off >= 1; off >>= 1)
    kmax = max(kmax, (unsigned)__shfl_xor((int)kmax, off, 64));
  const float smax = key2f(kmax);

  unsigned lo = 0u, hi = 0xFFFFFFFFu;
  while (lo < hi) {  // find max t with count(key >= t) >= 64
    const unsigned span = hi - lo;
    const unsigned mid = lo + (span >> 1) + (span & 1u);
    int c = 0;
#pragma unroll
    for (int q = 0; q < 32; ++q) c += (kk[q] >= mid) ? 1 : 0;
#pragma unroll
    for (int off = 32; off >= 1; off >>= 1) c += __shfl_xor(c, off, 64);
    if (c >= K_) lo = mid; else hi = mid - 1;
  }
  const unsigned V = lo;
  int cg = 0;
#pragma unroll
  for (int q = 0; q < 32; ++q) cg += (kk[q] > V) ? 1 : 0;
#pragma unroll
  for (int off = 32; off >= 1; off >>= 1) cg += __shfl_xor(cg, off, 64);
  const int m = K_ - cg;  // #ties (==V) to take, lowest index first (lax.top_k stable)

  {
    const unsigned long long lmlt = (1ull << ln) - 1ull;
    int gbase = 0, etaken = 0;
#pragma unroll
    for (int q = 0; q < 32; ++q) {
      const unsigned key = kk[q];
      const int l = ln + (q << 6);  // lane order == index order within chunk
      const bool gt = key > V;
      const bool eq = key == V;
      const unsigned long long bgt = __ballot(gt);
      const unsigned long long beq = __ballot(eq);
      if (gt) {
        const int pos = gbase + __popcll(bgt & lmlt);
        sidx[w][pos] = l;
        sw[w][pos] = expf(key2f(key) - smax);
      }
      const int navail = __popcll(beq);
      const int take = min(m - etaken, navail);
      if (eq) {
        const int rk = __popcll(beq & lmlt);
        if (rk < take) {
          const int pos = 63 - (etaken + rk);  // ties fill from the back
          sidx[w][pos] = l;
          sw[w][pos] = expf(key2f(key) - smax);
        }
      }
      gbase += __popcll(bgt);
      etaken += take;
    }
  }
  // no barrier: sidx/sw written and read by the same wave

  // ---------- gather + softmax-weighted sum of raw seq rows ----------
  {
    const int cg4 = ln & 15;  // float4 column group
    const int rg = ln >> 4;   // row subgroup 0..3
    float4 sv = make_float4(0.f, 0.f, 0.f, 0.f);
    float z = 0.f;
#pragma unroll
    for (int q = 0; q < 16; ++q) {
      const int sl = (q << 2) + rg;
      const int idx = sidx[w][sl];
      const float wt = sw[w][sl];
      const float4 v =
          *reinterpret_cast<const float4*>(seqb + (size_t)idx * 64 + (cg4 << 2));
      sv.x = fmaf(wt, v.x, sv.x);
      sv.y = fmaf(wt, v.y, sv.y);
      sv.z = fmaf(wt, v.z, sv.z);
      sv.w = fmaf(wt, v.w, sv.w);
      z += wt;
    }
#pragma unroll
    for (int off = 16; off <= 32; off <<= 1) {
      sv.x += __shfl_xor(sv.x, off, 64);
      sv.y += __shfl_xor(sv.y, off, 64);
      sv.z += __shfl_xor(sv.z, off, 64);
      sv.w += __shfl_xor(sv.w, off, 64);
      z += __shfl_xor(z, off, 64);
    }
    if (rg == 0) {  // lanes 0..15 hold the reduced result
      const float inv = 1.f / z;
      svec[w][(cg4 << 2) + 0] = sv.x * inv;
      svec[w][(cg4 << 2) + 1] = sv.y * inv;
      svec[w][(cg4 << 2) + 2] = sv.z * inv;
      svec[w][(cg4 << 2) + 3] = sv.w * inv;
    }
  }
  __syncthreads();

  // ---------- epilogue: out[b,:] = sum_h svec_h @ M_h ----------
  {
    float o = 0.f;
    const float* __restrict__ Mh = M + (w << 12);
#pragma unroll
    for (int i = 0; i < 64; ++i) o = fmaf(svec[w][i], Mh[(i << 6) + ln], o);
    part[w][ln] = o;
  }
  __syncthreads();
  if (tid < 64)
    out[(size_t)b * 64 + tid] = part[0][tid] + part[1][tid] + part[2][tid] + part[3][tid];
}

extern "C" void kernel_launch(void* const* d_in, const int* in_sizes, int n_in,
                              void* d_out, int out_size, void* d_ws, size_t ws_size,
                              hipStream_t stream) {
  const float* target = (const float*)d_in[0];
  const float* seq    = (const float*)d_in[1];
  const int*   mask   = (const int*)d_in[2];
  const float* Wq     = (const float*)d_in[3];
  const float* Wh     = (const float*)d_in[4];
  const float* Wv     = (const float*)d_in[5];
  const float* Wo     = (const float*)d_in[6];
  float* out  = (float*)d_out;
  float* weff = (float*)d_ws;                   // B*H*64 floats = 1 MB
  float* M    = weff + (size_t)B_ * H_ * 64;    // H*64*64 floats = 64 KB

  prep_weff_k<<<B_, 64, 0, stream>>>(target, Wq, Wh, weff);
  prep_M_k<<<64, 256, 0, stream>>>(Wv, Wo, M);
  attn_main_k<<<B_, 256, 0, stream>>>(seq, mask, weff, M, out);
}